// Round 10
// baseline (1974.293 us; speedup 1.0000x reference)
//
#include <hip/hip_runtime.h>
#include <math.h>

#define BB 2
#define LL 2048
#define SS 2048
#define HH 8
#define EE 64
#define DD 64
// softmax scale = 1/sqrt(E) = 0.125

// ws layout (256 KB):
//   [0, 128K)    : m32  (B*H*L floats) -- BLAS-grid fp32 M_sp
//   [128K, 256K) : rank (B*H*L ints)   -- rank[src row] = output row

// ---------- A: BLAS/XLA-grid fp32 M_sp (THE sort key) ---------------------
// score(s) = sequential FMA chain over e ascending, single accumulator:
//   c = 0; for e in 0..63: c = fmaf(q[e], k[e], c)
// (OpenBLAS sgemm micro-kernel and Eigen/XLA gebp both round exactly this
// way per C element.) Row-sum term: numpy fp32 pairwise structure
// (8-accumulator 128-blocks, exact-halves binary tree). Max exact over the
// same grid. Final M_sp = fl32(max - fl32(sum * 2^-11)).
__global__ __launch_bounds__(256, 2)
void msp_blas(const float* __restrict__ Q, const float* __restrict__ K,
              float* __restrict__ m32) {
#pragma clang fp contract(off)
    const int bid = blockIdx.x;          // B*H*32 = 512
    const int lt = bid & 31, bh = bid >> 5;
    const int h = bh & 7, b = bh >> 3;
    const int t = threadIdx.x, lq = t & 63, w = t >> 6;
    const int l = lt * 64 + lq;

    float qf[64];
    const float4* qrow = (const float4*)(Q + (((size_t)b * LL + l) * HH + h) * EE);
#pragma unroll
    for (int i = 0; i < 16; i++) {
        float4 v = qrow[i];
        qf[4*i] = v.x; qf[4*i+1] = v.y; qf[4*i+2] = v.z; qf[4*i+3] = v.w;
    }
    const size_t kvbase = ((size_t)b * SS * HH + h) * EE;

    float mx = -1e30f;
    float blk[4];                        // four 128-blocks per wave (512 keys)
    int sc = w * 512;
#pragma unroll 1
    for (int lf = 0; lf < 4; ++lf) {
        float r[8];                      // numpy pairwise 8-accumulator base
#pragma unroll 1
        for (int i8 = 0; i8 < 16; ++i8) {
            // 8 scores concurrently (ILP); each is its own strict
            // sequential fmaf chain over e = 0..63 ascending.
            float c[8];
#pragma unroll
            for (int j = 0; j < 8; j++) c[j] = 0.f;
            const float* kb = K + kvbase + (size_t)sc * (HH * EE);
#pragma unroll
            for (int e4 = 0; e4 < 16; ++e4) {
#pragma unroll
                for (int j = 0; j < 8; j++) {
                    const float4 kv =
                        *(const float4*)(kb + (size_t)j * (HH * EE) + e4 * 4);
                    c[j] = fmaf(qf[4*e4+0], kv.x, c[j]);
                    c[j] = fmaf(qf[4*e4+1], kv.y, c[j]);
                    c[j] = fmaf(qf[4*e4+2], kv.z, c[j]);
                    c[j] = fmaf(qf[4*e4+3], kv.w, c[j]);
                }
            }
#pragma unroll
            for (int j = 0; j < 8; j++) {
                mx = fmaxf(mx, c[j]);
                if (i8 == 0) r[j] = c[j];
                else         r[j] = __fadd_rn(r[j], c[j]);
            }
            sc += 8;
        }
        blk[lf] = __fadd_rn(
            __fadd_rn(__fadd_rn(r[0], r[1]), __fadd_rn(r[2], r[3])),
            __fadd_rn(__fadd_rn(r[4], r[5]), __fadd_rn(r[6], r[7])));
    }
    // pairwise recursion over blocks: pw(512) = (B0+B1)+(B2+B3)
    const float sub = __fadd_rn(__fadd_rn(blk[0], blk[1]),
                                __fadd_rn(blk[2], blk[3]));

    __shared__ float smx[4][64], ssub[4][64];
    smx[w][lq] = mx; ssub[w][lq] = sub;
    __syncthreads();
    if (w == 0) {
        const float m_all = fmaxf(fmaxf(smx[0][lq], smx[1][lq]),
                                  fmaxf(smx[2][lq], smx[3][lq]));
        // pw(2048) = (W0+W1)+(W2+W3)
        const float s2048 = __fadd_rn(__fadd_rn(ssub[0][lq], ssub[1][lq]),
                                      __fadd_rn(ssub[2][lq], ssub[3][lq]));
        const float mean = __fmul_rn(s2048, 0.00048828125f);  // /2048 exact
        m32[((size_t)bh << 11) + l] = __fsub_rn(m_all, mean);
    }
}

// ---------- B: descending sort, ties -> lower index first -----------------
__global__ __launch_bounds__(256)
void sort_rank(const float* __restrict__ m32, int* __restrict__ rank) {
    __shared__ unsigned int k1[2048];
    __shared__ int pay[2048];
    const int bh = blockIdx.x;
    const int t = threadIdx.x;
    for (int i = t; i < 2048; i += 256) {
        unsigned int u = __float_as_uint(m32[((size_t)bh << 11) + i]);
        u = (u & 0x80000000u) ? ~u : (u | 0x80000000u);
        k1[i] = u; pay[i] = i;
    }
    __syncthreads();
    for (int k = 2; k <= 2048; k <<= 1) {
        for (int j = k >> 1; j > 0; j >>= 1) {
            for (int i = t; i < 2048; i += 256) {
                const int ixj = i ^ j;
                if (ixj > i) {
                    unsigned int a1 = k1[i], c1 = k1[ixj];
                    int pa = pay[i], pc = pay[ixj];
                    const bool pre = (a1 > c1) || (a1 == c1 && pa < pc);
                    const bool dir = ((i & k) == 0);
                    if (dir != pre) {
                        k1[i] = c1; k1[ixj] = a1;
                        pay[i] = pc; pay[ixj] = pa;
                    }
                }
            }
            __syncthreads();
        }
    }
    for (int i = t; i < 2048; i += 256)
        rank[((size_t)bh << 11) + pay[i]] = i;   // inverse permutation
}

// ---------- C: flash attention, row written straight to its rank ----------
__global__ __launch_bounds__(256, 2)
void flash_scatter(const float* __restrict__ Q, const float* __restrict__ K,
                   const float* __restrict__ V, const int* __restrict__ rank,
                   float* __restrict__ out) {
    const int bid = blockIdx.x;          // 512
    const int lt = bid & 31, bh = bid >> 5;
    const int h = bh & 7, b = bh >> 3;
    const int t = threadIdx.x, lq = t & 63, w = t >> 6;
    const int l = lt * 64 + lq;

    const float4* qrow = (const float4*)(Q + (((size_t)b * LL + l) * HH + h) * EE);
    float4 q[16];
#pragma unroll
    for (int i = 0; i < 16; i++) q[i] = qrow[i];

    float4 acc[16];
#pragma unroll
    for (int i = 0; i < 16; i++) acc[i] = make_float4(0.f, 0.f, 0.f, 0.f);
    float mprev = -1e30f, mval = -1e30f, ell = 0.f;

    const size_t kvbase = ((size_t)b * SS * HH + h) * EE;
    const int s0 = w * 512;

    for (int sc = s0; sc < s0 + 512; sc += 8) {
        float scv[8];
#pragma unroll
        for (int j = 0; j < 8; j++) {
            const float4* kr = (const float4*)(K + kvbase + (size_t)(sc + j) * (HH * EE));
            float d0 = 0.f, d1 = 0.f, d2 = 0.f, d3 = 0.f;
#pragma unroll
            for (int i = 0; i < 16; i++) {
                float4 kv = kr[i];
                d0 = fmaf(q[i].x, kv.x, d0);
                d1 = fmaf(q[i].y, kv.y, d1);
                d2 = fmaf(q[i].z, kv.z, d2);
                d3 = fmaf(q[i].w, kv.w, d3);
            }
            scv[j] = (d0 + d1) + (d2 + d3);
        }
        float mt = scv[0];
#pragma unroll
        for (int j = 1; j < 8; j++) mt = fmaxf(mt, scv[j]);
        mval = fmaxf(mval, mt);
        if (mval > mprev) {
            const float alpha = __expf((mprev - mval) * 0.125f);
            ell *= alpha;
#pragma unroll
            for (int i = 0; i < 16; i++) {
                acc[i].x *= alpha; acc[i].y *= alpha;
                acc[i].z *= alpha; acc[i].w *= alpha;
            }
        }
#pragma unroll
        for (int j = 0; j < 8; j++) {
            const float p = __expf((scv[j] - mval) * 0.125f);
            ell += p;
            const float4* vr = (const float4*)(V + kvbase + (size_t)(sc + j) * (HH * DD));
#pragma unroll
            for (int i = 0; i < 16; i++) {
                float4 vv = vr[i];
                acc[i].x = fmaf(p, vv.x, acc[i].x);
                acc[i].y = fmaf(p, vv.y, acc[i].y);
                acc[i].z = fmaf(p, vv.z, acc[i].z);
                acc[i].w = fmaf(p, vv.w, acc[i].w);
            }
        }
        mprev = mval;
    }

    __shared__ float sm[2][64], sell[2][64];
    __shared__ float sacc[2][64][68];

    if (w >= 2) {
        const int slot = w - 2;
        sm[slot][lq] = mval; sell[slot][lq] = ell;
        float4* pa = (float4*)&sacc[slot][lq][0];
#pragma unroll
        for (int i = 0; i < 16; i++) pa[i] = acc[i];
    }
    __syncthreads();
    if (w < 2) {
        const float pm = sm[w][lq], pell = sell[w][lq];
        const float mn = fmaxf(mval, pm);
        const float a1 = __expf((mval - mn) * 0.125f);
        const float a2 = __expf((pm - mn) * 0.125f);
        ell = ell * a1 + pell * a2;
        const float4* pa = (const float4*)&sacc[w][lq][0];
#pragma unroll
        for (int i = 0; i < 16; i++) {
            float4 pv = pa[i];
            acc[i].x = acc[i].x * a1 + pv.x * a2;
            acc[i].y = acc[i].y * a1 + pv.y * a2;
            acc[i].z = acc[i].z * a1 + pv.z * a2;
            acc[i].w = acc[i].w * a1 + pv.w * a2;
        }
        mval = mn;
    }
    __syncthreads();
    if (w == 1) {
        sm[1][lq] = mval; sell[1][lq] = ell;
        float4* pa = (float4*)&sacc[1][lq][0];
#pragma unroll
        for (int i = 0; i < 16; i++) pa[i] = acc[i];
    }
    __syncthreads();
    if (w == 0) {
        const float pm = sm[1][lq], pell = sell[1][lq];
        const float mn = fmaxf(mval, pm);
        const float a1 = __expf((mval - mn) * 0.125f);
        const float a2 = __expf((pm - mn) * 0.125f);
        ell = ell * a1 + pell * a2;
        const float4* pa = (const float4*)&sacc[1][lq][0];
        const float inv = 1.0f / ell;
        const int rk = rank[((size_t)bh << 11) + l];
        float4* orow = (float4*)(out + (((size_t)b * LL + rk) * HH + h) * DD);
#pragma unroll
        for (int i = 0; i < 16; i++) {
            float4 pv = pa[i];
            float4 o;
            o.x = (acc[i].x * a1 + pv.x * a2) * inv;
            o.y = (acc[i].y * a1 + pv.y * a2) * inv;
            o.z = (acc[i].z * a1 + pv.z * a2) * inv;
            o.w = (acc[i].w * a1 + pv.w * a2) * inv;
            orow[i] = o;
        }
    }
}

extern "C" void kernel_launch(void* const* d_in, const int* in_sizes, int n_in,
                              void* d_out, int out_size, void* d_ws, size_t ws_size,
                              hipStream_t stream) {
    const float* Q = (const float*)d_in[0];
    const float* K = (const float*)d_in[1];
    const float* V = (const float*)d_in[2];
    float* out = (float*)d_out;

    float* m32  = (float*)d_ws;                          // 128 KB
    int*   rank = (int*)((char*)d_ws + 131072);          // 128 KB

    msp_blas<<<BB * HH * (LL / 64), 256, 0, stream>>>(Q, K, m32);
    sort_rank<<<BB * HH, 256, 0, stream>>>(m32, rank);
    flash_scatter<<<BB * HH * (LL / 64), 256, 0, stream>>>(Q, K, V, rank, out);
}

// Round 11
// 1000.680 us; speedup vs baseline: 1.9730x; 1.9730x over previous
//
#include <hip/hip_runtime.h>
#include <math.h>

#define BB 2
#define LL 2048
#define SS 2048
#define HH 8
#define EE 64
#define DD 64
// softmax scale = 1/sqrt(E) = 0.125

// ws layout (384 KB):
//   [0, 128K)     : m32  (B*H*L floats) -- BLAS-grid fp32 M_sp (bit-exact)
//   [128K, 256K)  : rank (B*H*L ints)   -- rank[src row] = output row
//   [256K, 384K)  : maxs (B*H*L floats) -- per-row score max (for 2-pass softmax)

// ---------- A: BLAS-grid fp32 M_sp, LDS-staged (arithmetic UNCHANGED) -----
// score(s) = sequential fmaf chain over e ascending (single accumulator) —
// this rounding sequence is the verified match to the np/jax reference grid.
// DO NOT alter the chain, the 8-acc pairwise base, or the combine trees.
__global__ __launch_bounds__(256, 2)
void msp_blas(const float* __restrict__ Q, const float* __restrict__ K,
              float* __restrict__ m32, float* __restrict__ maxs) {
#pragma clang fp contract(off)
    const int bid = blockIdx.x;          // B*H*32 = 512
    const int lt = bid & 31, bh = bid >> 5;
    const int h = bh & 7, b = bh >> 3;
    const int t = threadIdx.x, lq = t & 63, w = t >> 6;
    const int l = lt * 64 + lq;

    __shared__ float ldsk[4][32][64];    // 32 KB: per-wave 32-s K sub-tile
    __shared__ float smx[4][64], ssub[4][64];

    float qf[64];
    const float4* qrow = (const float4*)(Q + (((size_t)b * LL + l) * HH + h) * EE);
#pragma unroll
    for (int i = 0; i < 16; i++) {
        float4 v = qrow[i];
        qf[4*i] = v.x; qf[4*i+1] = v.y; qf[4*i+2] = v.z; qf[4*i+3] = v.w;
    }
    const size_t kvbase = ((size_t)b * SS * HH + h) * EE;

    float mx = -1e30f;
    float blk[4];
#pragma unroll 1
    for (int lf = 0; lf < 4; ++lf) {
        float r[8] = {0,0,0,0,0,0,0,0};
#pragma unroll 1
        for (int rnd = 0; rnd < 4; ++rnd) {
            __syncthreads();             // prior round's reads complete
            // stage 4 waves x 32 rows x 64 floats (coalesced 256B segments)
#pragma unroll
            for (int kk = 0; kk < 8; ++kk) {
                const int f4  = kk * 256 + t;     // 0..2047
                const int ws_ = f4 >> 9;
                const int row = (f4 >> 4) & 31;
                const int col = f4 & 15;
                const int s   = ws_ * 512 + lf * 128 + rnd * 32 + row;
                *(float4*)&ldsk[ws_][row][col * 4] =
                    *(const float4*)(K + kvbase + (size_t)s * (HH * EE) + col * 4);
            }
            __syncthreads();
#pragma unroll 1
            for (int g = 0; g < 4; ++g) {
                const int i8 = rnd * 4 + g;
                // 8 scores; each a strict sequential fmaf chain e=0..63 asc.
                float c[8];
#pragma unroll
                for (int j = 0; j < 8; j++) c[j] = 0.f;
#pragma unroll
                for (int e4 = 0; e4 < 16; ++e4) {
#pragma unroll
                    for (int j = 0; j < 8; j++) {
                        const float4 kv = *(const float4*)&ldsk[w][g * 8 + j][e4 * 4];
                        c[j] = fmaf(qf[4*e4+0], kv.x, c[j]);
                        c[j] = fmaf(qf[4*e4+1], kv.y, c[j]);
                        c[j] = fmaf(qf[4*e4+2], kv.z, c[j]);
                        c[j] = fmaf(qf[4*e4+3], kv.w, c[j]);
                    }
                }
#pragma unroll
                for (int j = 0; j < 8; j++) {
                    mx = fmaxf(mx, c[j]);
                    if (i8 == 0) r[j] = c[j];
                    else         r[j] = __fadd_rn(r[j], c[j]);
                }
            }
        }
        blk[lf] = __fadd_rn(
            __fadd_rn(__fadd_rn(r[0], r[1]), __fadd_rn(r[2], r[3])),
            __fadd_rn(__fadd_rn(r[4], r[5]), __fadd_rn(r[6], r[7])));
    }
    const float sub = __fadd_rn(__fadd_rn(blk[0], blk[1]),
                                __fadd_rn(blk[2], blk[3]));

    smx[w][lq] = mx; ssub[w][lq] = sub;
    __syncthreads();
    if (w == 0) {
        const float m_all = fmaxf(fmaxf(smx[0][lq], smx[1][lq]),
                                  fmaxf(smx[2][lq], smx[3][lq]));
        const float s2048 = __fadd_rn(__fadd_rn(ssub[0][lq], ssub[1][lq]),
                                      __fadd_rn(ssub[2][lq], ssub[3][lq]));
        const float mean = __fmul_rn(s2048, 0.00048828125f);  // /2048 exact
        m32[((size_t)bh << 11) + l]  = __fsub_rn(m_all, mean);
        maxs[((size_t)bh << 11) + l] = m_all;
    }
}

// ---------- B: descending sort, ties -> lower index first -----------------
__global__ __launch_bounds__(256)
void sort_rank(const float* __restrict__ m32, int* __restrict__ rank) {
    __shared__ unsigned int k1[2048];
    __shared__ int pay[2048];
    const int bh = blockIdx.x;
    const int t = threadIdx.x;
    for (int i = t; i < 2048; i += 256) {
        unsigned int u = __float_as_uint(m32[((size_t)bh << 11) + i]);
        u = (u & 0x80000000u) ? ~u : (u | 0x80000000u);
        k1[i] = u; pay[i] = i;
    }
    __syncthreads();
    for (int k = 2; k <= 2048; k <<= 1) {
        for (int j = k >> 1; j > 0; j >>= 1) {
            for (int i = t; i < 2048; i += 256) {
                const int ixj = i ^ j;
                if (ixj > i) {
                    unsigned int a1 = k1[i], c1 = k1[ixj];
                    int pa = pay[i], pc = pay[ixj];
                    const bool pre = (a1 > c1) || (a1 == c1 && pa < pc);
                    const bool dir = ((i & k) == 0);
                    if (dir != pre) {
                        k1[i] = c1; k1[ixj] = a1;
                        pay[i] = pc; pay[ixj] = pa;
                    }
                }
            }
            __syncthreads();
        }
    }
    for (int i = t; i < 2048; i += 256)
        rank[((size_t)bh << 11) + pay[i]] = i;   // inverse permutation
}

// ---------- C: two-pass flash (precomputed max), LDS-staged, scatter ------
__global__ __launch_bounds__(256, 2)
void flash2(const float* __restrict__ Q, const float* __restrict__ K,
            const float* __restrict__ V, const float* __restrict__ maxs,
            const int* __restrict__ rank, float* __restrict__ out) {
    const int bid = blockIdx.x;          // 512
    const int lt = bid & 31, bh = bid >> 5;
    const int h = bh & 7, b = bh >> 3;
    const int t = threadIdx.x, lq = t & 63, w = t >> 6;
    const int l = lt * 64 + lq;

    __shared__ float ldsb[16384];        // 64 KB: K [0,8192), V [8192,16384)
    __shared__ float pEll[3][64];

    const float4* qrow = (const float4*)(Q + (((size_t)b * LL + l) * HH + h) * EE);
    float4 q[16];
#pragma unroll
    for (int i = 0; i < 16; i++) q[i] = qrow[i];

    float4 acc[16];
#pragma unroll
    for (int i = 0; i < 16; i++) acc[i] = make_float4(0.f, 0.f, 0.f, 0.f);

    const float m = maxs[((size_t)bh << 11) + l];
    const float negpm = -0.125f * m;
    float ell = 0.f;
    const size_t kvbase = ((size_t)b * SS * HH + h) * EE;

#pragma unroll 1
    for (int rnd = 0; rnd < 16; ++rnd) {
        __syncthreads();
        // stage K and V: 4 waves x 32 rows x 64 floats each
#pragma unroll
        for (int kk = 0; kk < 8; ++kk) {
            const int f4  = kk * 256 + t;
            const int ws_ = f4 >> 9;
            const int row = (f4 >> 4) & 31;
            const int col = f4 & 15;
            const int s   = ws_ * 512 + rnd * 32 + row;
            const size_t goff = kvbase + (size_t)s * (HH * EE) + col * 4;
            *(float4*)&ldsb[(ws_ * 32 + row) * 64 + col * 4] =
                *(const float4*)(K + goff);
            *(float4*)&ldsb[8192 + (ws_ * 32 + row) * 64 + col * 4] =
                *(const float4*)(V + goff);
        }
        __syncthreads();
        const float* kbase = &ldsb[(w * 32) * 64];
        const float* vbase = &ldsb[8192 + (w * 32) * 64];
#pragma unroll 4
        for (int j = 0; j < 32; ++j) {
            const float4* kr = (const float4*)(kbase + j * 64);
            float d0 = 0.f, d1 = 0.f, d2 = 0.f, d3 = 0.f;
#pragma unroll
            for (int i = 0; i < 16; i++) {
                float4 kv = kr[i];
                d0 = fmaf(q[i].x, kv.x, d0);
                d1 = fmaf(q[i].y, kv.y, d1);
                d2 = fmaf(q[i].z, kv.z, d2);
                d3 = fmaf(q[i].w, kv.w, d3);
            }
            const float s = (d0 + d1) + (d2 + d3);
            const float p = __expf(fmaf(s, 0.125f, negpm));
            ell += p;
            const float4* vr = (const float4*)(vbase + j * 64);
#pragma unroll
            for (int i = 0; i < 16; i++) {
                float4 vv = vr[i];
                acc[i].x = fmaf(p, vv.x, acc[i].x);
                acc[i].y = fmaf(p, vv.y, acc[i].y);
                acc[i].z = fmaf(p, vv.z, acc[i].z);
                acc[i].w = fmaf(p, vv.w, acc[i].w);
            }
        }
    }

    // epilogue: same max everywhere -> partials just add (no alphas)
    __syncthreads();
    if (w > 0) {
        float* pa = &ldsb[(w - 1) * 64 * 68 + lq * 68];  // 68-stride, 16B-aligned
#pragma unroll
        for (int i = 0; i < 16; i++) *(float4*)(pa + i * 4) = acc[i];
        pEll[w - 1][lq] = ell;
    }
    __syncthreads();
    if (w == 0) {
#pragma unroll
        for (int p2 = 0; p2 < 3; ++p2) {
            const float* pa = &ldsb[p2 * 64 * 68 + lq * 68];
            ell += pEll[p2][lq];
#pragma unroll
            for (int i = 0; i < 16; i++) {
                float4 pv = *(const float4*)(pa + i * 4);
                acc[i].x += pv.x; acc[i].y += pv.y;
                acc[i].z += pv.z; acc[i].w += pv.w;
            }
        }
        const float inv = 1.0f / ell;
        const int rk = rank[((size_t)bh << 11) + l];
        float4* orow = (float4*)(out + (((size_t)b * LL + rk) * HH + h) * DD);
#pragma unroll
        for (int i = 0; i < 16; i++) {
            float4 o;
            o.x = acc[i].x * inv; o.y = acc[i].y * inv;
            o.z = acc[i].z * inv; o.w = acc[i].w * inv;
            orow[i] = o;
        }
    }
}

extern "C" void kernel_launch(void* const* d_in, const int* in_sizes, int n_in,
                              void* d_out, int out_size, void* d_ws, size_t ws_size,
                              hipStream_t stream) {
    const float* Q = (const float*)d_in[0];
    const float* K = (const float*)d_in[1];
    const float* V = (const float*)d_in[2];
    float* out = (float*)d_out;

    float* m32  = (float*)d_ws;                          // 128 KB
    int*   rank = (int*)((char*)d_ws + 131072);          // 128 KB
    float* maxs = (float*)((char*)d_ws + 262144);        // 128 KB

    msp_blas<<<BB * HH * (LL / 64), 256, 0, stream>>>(Q, K, m32, maxs);
    sort_rank<<<BB * HH, 256, 0, stream>>>(m32, rank);
    flash2<<<BB * HH * (LL / 64), 256, 0, stream>>>(Q, K, V, maxs, rank, out);
}

// Round 12
// 754.634 us; speedup vs baseline: 2.6162x; 1.3260x over previous
//
#include <hip/hip_runtime.h>
#include <math.h>

#define BB 2
#define LL 2048
#define SS 2048
#define HH 8
#define EE 64
#define DD 64
#define HE (HH * EE)   // 512
// softmax scale = 1/sqrt(E) = 0.125

// ws layout (384 KB):
//   [0, 128K)     : m32  (B*H*L floats) -- BLAS-grid fp32 M_sp (bit-exact)
//   [128K, 256K)  : rank (B*H*L ints)
//   [256K, 384K)  : maxs (B*H*L floats)

typedef __attribute__((ext_vector_type(8))) short   bf16x8;   // MFMA A/B frag
typedef __attribute__((ext_vector_type(4))) float   f32x4;    // MFMA C/D frag
typedef __attribute__((ext_vector_type(8))) unsigned short u16x8;
typedef __attribute__((ext_vector_type(4))) unsigned short u16x4;

__device__ __forceinline__ unsigned short f2bf(float x) {   // fp32 -> bf16 RNE
    unsigned int u = __float_as_uint(x);
    return (unsigned short)((u + 0x7FFFu + ((u >> 16) & 1u)) >> 16);
}

// ---------- A: BLAS-grid fp32 M_sp, K via wave-uniform (scalar) loads -----
// Arithmetic sequence IDENTICAL to the verified R10/R11 kernel:
// score = sequential fmaf chain e=0..63 asc, single accumulator;
// row-sum = 8-acc pairwise base + exact-halves trees. DO NOT REORDER.
__global__ __launch_bounds__(256, 2)
void msp_blas(const float* __restrict__ Q, const float* __restrict__ K,
              float* __restrict__ m32, float* __restrict__ maxs) {
#pragma clang fp contract(off)
    const int bid = blockIdx.x;          // B*H*32 = 512
    const int lt = bid & 31, bh = bid >> 5;
    const int h = bh & 7, b = bh >> 3;
    const int t = threadIdx.x, lq = t & 63, w = t >> 6;
    const int l = lt * 64 + lq;

    float qf[64];
    const float4* qrow = (const float4*)(Q + (((size_t)b * LL + l) * HH + h) * EE);
#pragma unroll
    for (int i = 0; i < 16; i++) {
        float4 v = qrow[i];
        qf[4*i] = v.x; qf[4*i+1] = v.y; qf[4*i+2] = v.z; qf[4*i+3] = v.w;
    }

    // wave-uniform K base -> compiler can emit s_load (SGPR) K fetches
    const int wu = __builtin_amdgcn_readfirstlane(w);
    const float* Kb = K + (((size_t)b * SS) * HH + h) * EE;

    float mx = -1e30f;
    float blk[4];
#pragma unroll 1
    for (int lf = 0; lf < 4; ++lf) {
        float r[8];
#pragma unroll 1
        for (int i8 = 0; i8 < 16; ++i8) {
            const int s0 = wu * 512 + lf * 128 + i8 * 8;
            float c[8];
#pragma unroll
            for (int j = 0; j < 8; j++) c[j] = 0.f;
#pragma unroll
            for (int e4 = 0; e4 < 16; ++e4) {
#pragma unroll
                for (int j = 0; j < 8; j++) {
                    const float4 kv =
                        *(const float4*)(Kb + (size_t)(s0 + j) * HE + e4 * 4);
                    c[j] = fmaf(qf[4*e4+0], kv.x, c[j]);
                    c[j] = fmaf(qf[4*e4+1], kv.y, c[j]);
                    c[j] = fmaf(qf[4*e4+2], kv.z, c[j]);
                    c[j] = fmaf(qf[4*e4+3], kv.w, c[j]);
                }
            }
#pragma unroll
            for (int j = 0; j < 8; j++) {
                mx = fmaxf(mx, c[j]);
                if (i8 == 0) r[j] = c[j];
                else         r[j] = __fadd_rn(r[j], c[j]);
            }
        }
        blk[lf] = __fadd_rn(
            __fadd_rn(__fadd_rn(r[0], r[1]), __fadd_rn(r[2], r[3])),
            __fadd_rn(__fadd_rn(r[4], r[5]), __fadd_rn(r[6], r[7])));
    }
    const float sub = __fadd_rn(__fadd_rn(blk[0], blk[1]),
                                __fadd_rn(blk[2], blk[3]));

    __shared__ float smx[4][64], ssub[4][64];
    smx[w][lq] = mx; ssub[w][lq] = sub;
    __syncthreads();
    if (w == 0) {
        const float m_all = fmaxf(fmaxf(smx[0][lq], smx[1][lq]),
                                  fmaxf(smx[2][lq], smx[3][lq]));
        const float s2048 = __fadd_rn(__fadd_rn(ssub[0][lq], ssub[1][lq]),
                                      __fadd_rn(ssub[2][lq], ssub[3][lq]));
        const float mean = __fmul_rn(s2048, 0.00048828125f);  // /2048 exact
        m32[((size_t)bh << 11) + l]  = __fsub_rn(m_all, mean);
        maxs[((size_t)bh << 11) + l] = m_all;
    }
}

// ---------- B: descending sort, ties -> lower index first -----------------
__global__ __launch_bounds__(256)
void sort_rank(const float* __restrict__ m32, int* __restrict__ rank) {
    __shared__ unsigned int k1[2048];
    __shared__ int pay[2048];
    const int bh = blockIdx.x;
    const int t = threadIdx.x;
    for (int i = t; i < 2048; i += 256) {
        unsigned int u = __float_as_uint(m32[((size_t)bh << 11) + i]);
        u = (u & 0x80000000u) ? ~u : (u | 0x80000000u);
        k1[i] = u; pay[i] = i;
    }
    __syncthreads();
    for (int k = 2; k <= 2048; k <<= 1) {
        for (int j = k >> 1; j > 0; j >>= 1) {
            for (int i = t; i < 2048; i += 256) {
                const int ixj = i ^ j;
                if (ixj > i) {
                    unsigned int a1 = k1[i], c1 = k1[ixj];
                    int pa = pay[i], pc = pay[ixj];
                    const bool pre = (a1 > c1) || (a1 == c1 && pa < pc);
                    const bool dir = ((i & k) == 0);
                    if (dir != pre) {
                        k1[i] = c1; k1[ixj] = a1;
                        pay[i] = pc; pay[ixj] = pa;
                    }
                }
            }
            __syncthreads();
        }
    }
    for (int i = t; i < 2048; i += 256)
        rank[((size_t)bh << 11) + pay[i]] = i;   // inverse permutation
}

// ---------- C: bf16 MFMA flash (two-pass softmax), scatter by rank --------
// Wave w owns 16 queries (rows lt*64 + w*16 .. +15) over the FULL S range.
// Per 64-s chunk: QK via mfma_16x16x32_bf16 (8), exp, P->LDS (A-layout),
// PV via mfma (8). K staged [s][e], V staged transposed [d][s], pitch 72
// bf16 (16B-aligned rows, bank-spread).
__global__ __launch_bounds__(256, 2)
void flash_mfma(const float* __restrict__ Q, const float* __restrict__ K,
                const float* __restrict__ V, const float* __restrict__ maxs,
                const int* __restrict__ rank, float* __restrict__ out) {
    __shared__ unsigned short ldsK[64 * 72];        // 9216 B
    __shared__ unsigned short ldsVT[64 * 72];       // 9216 B  (V transposed)
    __shared__ unsigned short ldsP[4 * 16 * 72];    // 9216 B  (per-wave P)

    const int bid = blockIdx.x;          // 512
    const int lt = bid & 31, bh = bid >> 5;
    const int h = bh & 7, b = bh >> 3;
    const int t = threadIdx.x, lane = t & 63, w = t >> 6;
    const int quad = lane >> 4, cl = lane & 15;

    const size_t kvbase = (((size_t)b * SS) * HH + h) * EE;

    // Q A-frags: A[m=cl][k=quad*8+j (+32*ef)]
    bf16x8 qa[2];
    {
        const float* qp = Q + (((size_t)b * LL + (lt * 64 + w * 16 + cl)) * HH + h) * EE
                          + quad * 8;
#pragma unroll
        for (int ef = 0; ef < 2; ++ef) {
            float4 a0 = *(const float4*)(qp + ef * 32);
            float4 a1 = *(const float4*)(qp + ef * 32 + 4);
            short* s = (short*)&qa[ef];
            s[0] = (short)f2bf(a0.x); s[1] = (short)f2bf(a0.y);
            s[2] = (short)f2bf(a0.z); s[3] = (short)f2bf(a0.w);
            s[4] = (short)f2bf(a1.x); s[5] = (short)f2bf(a1.y);
            s[6] = (short)f2bf(a1.z); s[7] = (short)f2bf(a1.w);
        }
    }

    // per-lane row constants (rows quad*4+reg)
    float negpm[4];
    int rk[4];
#pragma unroll
    for (int reg = 0; reg < 4; ++reg) {
        const int qg = lt * 64 + w * 16 + quad * 4 + reg;
        negpm[reg] = -0.125f * maxs[((size_t)bh << 11) + qg];
        rk[reg]    = rank[((size_t)bh << 11) + qg];
    }

    f32x4 accO[4];
#pragma unroll
    for (int nt = 0; nt < 4; ++nt) accO[nt] = (f32x4){0.f, 0.f, 0.f, 0.f};
    float ell[4] = {0.f, 0.f, 0.f, 0.f};

    const int pbase = w * (16 * 72);

#pragma unroll 1
    for (int c0 = 0; c0 < SS; c0 += 64) {
        __syncthreads();
        // ---- stage K[s][e] -> bf16, row-major pitch 72 ----
        {
            const int row = t >> 2, col0 = (t & 3) * 16;
            const float* gp = K + kvbase + (size_t)(c0 + row) * HE + col0;
            float4 f0 = ((const float4*)gp)[0];
            float4 f1 = ((const float4*)gp)[1];
            float4 f2 = ((const float4*)gp)[2];
            float4 f3 = ((const float4*)gp)[3];
            u16x8 w0 = { f2bf(f0.x), f2bf(f0.y), f2bf(f0.z), f2bf(f0.w),
                         f2bf(f1.x), f2bf(f1.y), f2bf(f1.z), f2bf(f1.w) };
            u16x8 w1 = { f2bf(f2.x), f2bf(f2.y), f2bf(f2.z), f2bf(f2.w),
                         f2bf(f3.x), f2bf(f3.y), f2bf(f3.z), f2bf(f3.w) };
            *(u16x8*)&ldsK[row * 72 + col0]     = w0;
            *(u16x8*)&ldsK[row * 72 + col0 + 8] = w1;
        }
        // ---- stage V transposed: VT[d][s] bf16, pitch 72 ----
        {
            const int s0 = (t & 15) * 4, d0 = (t >> 4) * 4;
            const float* gv = V + kvbase + (size_t)(c0 + s0) * HE + d0;
            float4 v0 = *(const float4*)(gv);
            float4 v1 = *(const float4*)(gv + HE);
            float4 v2 = *(const float4*)(gv + 2 * HE);
            float4 v3 = *(const float4*)(gv + 3 * HE);
            u16x4 p0 = { f2bf(v0.x), f2bf(v1.x), f2bf(v2.x), f2bf(v3.x) };
            u16x4 p1 = { f2bf(v0.y), f2bf(v1.y), f2bf(v2.y), f2bf(v3.y) };
            u16x4 p2 = { f2bf(v0.z), f2bf(v1.z), f2bf(v2.z), f2bf(v3.z) };
            u16x4 p3 = { f2bf(v0.w), f2bf(v1.w), f2bf(v2.w), f2bf(v3.w) };
            *(u16x4*)&ldsVT[(d0 + 0) * 72 + s0] = p0;
            *(u16x4*)&ldsVT[(d0 + 1) * 72 + s0] = p1;
            *(u16x4*)&ldsVT[(d0 + 2) * 72 + s0] = p2;
            *(u16x4*)&ldsVT[(d0 + 3) * 72 + s0] = p3;
        }
        __syncthreads();

        // ---- QK^T: S[m=q16][n=s64] = A(Q) x B(K), B[k=e][n=s]=K[s][e] ----
        f32x4 Sc[4];
#pragma unroll
        for (int nt = 0; nt < 4; ++nt) {
            bf16x8 bk0 = *(const bf16x8*)&ldsK[(nt * 16 + cl) * 72 + quad * 8];
            bf16x8 bk1 = *(const bf16x8*)&ldsK[(nt * 16 + cl) * 72 + quad * 8 + 32];
            f32x4 z = (f32x4){0.f, 0.f, 0.f, 0.f};
            z = __builtin_amdgcn_mfma_f32_16x16x32_bf16(qa[0], bk0, z, 0, 0, 0);
            z = __builtin_amdgcn_mfma_f32_16x16x32_bf16(qa[1], bk1, z, 0, 0, 0);
            Sc[nt] = z;
        }

        // ---- softmax numerator + P (bf16) into A-layout LDS ----
#pragma unroll
        for (int nt = 0; nt < 4; ++nt) {
#pragma unroll
            for (int reg = 0; reg < 4; ++reg) {
                const float p = __expf(fmaf(Sc[nt][reg], 0.125f, negpm[reg]));
                ell[reg] += p;
                ldsP[pbase + (quad * 4 + reg) * 72 + nt * 16 + cl] = f2bf(p);
            }
        }

        // ---- PV: O[m=q16][n=d64] += A(P) x B(V), B[k=s][n=d]=VT[d][s] ----
        bf16x8 pa0 = *(const bf16x8*)&ldsP[pbase + cl * 72 + quad * 8];
        bf16x8 pa1 = *(const bf16x8*)&ldsP[pbase + cl * 72 + quad * 8 + 32];
#pragma unroll
        for (int nt = 0; nt < 4; ++nt) {
            bf16x8 bv0 = *(const bf16x8*)&ldsVT[(nt * 16 + cl) * 72 + quad * 8];
            bf16x8 bv1 = *(const bf16x8*)&ldsVT[(nt * 16 + cl) * 72 + quad * 8 + 32];
            accO[nt] = __builtin_amdgcn_mfma_f32_16x16x32_bf16(pa0, bv0, accO[nt], 0, 0, 0);
            accO[nt] = __builtin_amdgcn_mfma_f32_16x16x32_bf16(pa1, bv1, accO[nt], 0, 0, 0);
        }
    }

    // ---- ell: reduce across the 16 lanes sharing each row (within quad) ----
#pragma unroll
    for (int reg = 0; reg < 4; ++reg) {
        float e = ell[reg];
        e += __shfl_xor(e, 1);
        e += __shfl_xor(e, 2);
        e += __shfl_xor(e, 4);
        e += __shfl_xor(e, 8);
        ell[reg] = 1.0f / e;
    }

    // ---- scatter O rows by rank ----
#pragma unroll
    for (int reg = 0; reg < 4; ++reg) {
        float* orow = out + (((size_t)b * LL + rk[reg]) * HH + h) * DD;
#pragma unroll
        for (int nt = 0; nt < 4; ++nt)
            orow[nt * 16 + cl] = accO[nt][reg] * ell[reg];
    }
}

extern "C" void kernel_launch(void* const* d_in, const int* in_sizes, int n_in,
                              void* d_out, int out_size, void* d_ws, size_t ws_size,
                              hipStream_t stream) {
    const float* Q = (const float*)d_in[0];
    const float* K = (const float*)d_in[1];
    const float* V = (const float*)d_in[2];
    float* out = (float*)d_out;

    float* m32  = (float*)d_ws;                          // 128 KB
    int*   rank = (int*)((char*)d_ws + 131072);          // 128 KB
    float* maxs = (float*)((char*)d_ws + 262144);        // 128 KB

    msp_blas<<<BB * HH * (LL / 64), 256, 0, stream>>>(Q, K, m32, maxs);
    sort_rank<<<BB * HH, 256, 0, stream>>>(m32, rank);
    flash_mfma<<<BB * HH * (LL / 64), 256, 0, stream>>>(Q, K, V, maxs, rank, out);
}